// Round 3
// baseline (684.144 us; speedup 1.0000x reference)
//
#include <hip/hip_runtime.h>

// Flash attention fwd: SQ=2048, B=2, H=16, D=64, fp32 in/out, bool mask.
// R3 = R2 with the cvt_pkrtz type fix: f16 pre-pass (Q scaled to exp2 domain,
// V pre-transposed) + global_load_lds DMA staging with XOR swizzle +
// double-buffered K/V LDS (1 barrier/tile) + exp2 softmax + packed converts.
// S^T formulation (q on MFMA lane dim).

using half2v  = __attribute__((ext_vector_type(2))) _Float16;
using half4v  = __attribute__((ext_vector_type(4))) _Float16;
using half8v  = __attribute__((ext_vector_type(8))) _Float16;
using fp16x2  = __attribute__((ext_vector_type(2))) __fp16;
using float4v = __attribute__((ext_vector_type(4))) float;
using uint4v  = __attribute__((ext_vector_type(4))) unsigned int;

#define AS1 __attribute__((address_space(1)))
#define AS3 __attribute__((address_space(3)))

constexpr int SQn = 2048;
constexpr int BHn = 32;            // B*H
constexpr int Dn  = 64;
constexpr int KT  = 64;            // k-tile
constexpr int NT  = SQn / KT;      // 32 tiles
constexpr int QTB = 128;           // q rows per block
constexpr int WQ  = 32;            // q rows per wave
constexpr int PSTR = 72;           // P LDS row stride (halves)
constexpr float QSCALE = 0.18033688011112042f;   // 0.125 * log2(e)
constexpr float MASKV  = -14426.95f;             // -10000 * log2(e)

__device__ __forceinline__ half2v pkrtz(float a, float b) {
    fp16x2 r = __builtin_amdgcn_cvt_pkrtz(a, b);
    return __builtin_bit_cast(half2v, r);
}

__device__ __forceinline__ void dma16(const _Float16* g, _Float16* l) {
    __builtin_amdgcn_global_load_lds((const AS1 unsigned int*)g,
                                     (AS3 unsigned int*)l, 16, 0, 0);
}

// ---- pre-pass 1: Q (scaled) and K fp32 -> f16, same [sq][bh][d] layout ----
__global__ __launch_bounds__(256)
void conv_qk(const float* __restrict__ Q, const float* __restrict__ K,
             _Float16* __restrict__ Qh, _Float16* __restrict__ Kh) {
    constexpr int half_n = (SQn * BHn * Dn) / 8;   // 524288 threads per tensor
    int t = blockIdx.x * 256 + threadIdx.x;
    const float* src = Q; _Float16* dst = Qh; float sc = QSCALE;
    if (t >= half_n) { src = K; dst = Kh; sc = 1.0f; t -= half_n; }
    float4v a = ((const float4v*)src)[2 * t];
    float4v b = ((const float4v*)src)[2 * t + 1];
    half8v h;
    ((half2v*)&h)[0] = pkrtz(a[0] * sc, a[1] * sc);
    ((half2v*)&h)[1] = pkrtz(a[2] * sc, a[3] * sc);
    ((half2v*)&h)[2] = pkrtz(b[0] * sc, b[1] * sc);
    ((half2v*)&h)[3] = pkrtz(b[2] * sc, b[3] * sc);
    ((half8v*)dst)[t] = h;
}

// ---- pre-pass 2: V fp32 [sq][bh][d] -> f16 transposed [bh][d][sq] ----
__global__ __launch_bounds__(256)
void trans_v(const float* __restrict__ V, _Float16* __restrict__ Vt) {
    __shared__ _Float16 T[64 * 72];
    const int tid = threadIdx.x;
    const int bh = blockIdx.x >> 5;
    const int k0 = (blockIdx.x & 31) * 64;
    {
        const int kl = tid >> 2, part = tid & 3;      // 64 rows x 16 floats
        const float* src = V + ((size_t)(k0 + kl) * BHn + bh) * Dn + part * 16;
        float4v a0 = ((const float4v*)src)[0], a1 = ((const float4v*)src)[1];
        float4v a2 = ((const float4v*)src)[2], a3 = ((const float4v*)src)[3];
        half8v h0, h1;
        ((half2v*)&h0)[0] = pkrtz(a0[0], a0[1]);
        ((half2v*)&h0)[1] = pkrtz(a0[2], a0[3]);
        ((half2v*)&h0)[2] = pkrtz(a1[0], a1[1]);
        ((half2v*)&h0)[3] = pkrtz(a1[2], a1[3]);
        ((half2v*)&h1)[0] = pkrtz(a2[0], a2[1]);
        ((half2v*)&h1)[1] = pkrtz(a2[2], a2[3]);
        ((half2v*)&h1)[2] = pkrtz(a3[0], a3[1]);
        ((half2v*)&h1)[3] = pkrtz(a3[2], a3[3]);
        *(half8v*)&T[kl * 72 + part * 16]     = h0;
        *(half8v*)&T[kl * 72 + part * 16 + 8] = h1;
    }
    __syncthreads();
    {
        const int d = tid >> 2, kc = tid & 3;         // 64 d-rows x 16 k
        half8v o0, o1;
#pragma unroll
        for (int j = 0; j < 8; ++j) o0[j] = T[(kc * 16 + j) * 72 + d];
#pragma unroll
        for (int j = 0; j < 8; ++j) o1[j] = T[(kc * 16 + 8 + j) * 72 + d];
        _Float16* dst = Vt + ((size_t)bh * Dn + d) * SQn + k0 + kc * 16;
        *(half8v*)dst       = o0;
        *(half8v*)(dst + 8) = o1;
    }
}

// ---- main flash kernel ----
__global__ __launch_bounds__(256, 2)
void fa_main(const _Float16* __restrict__ Qh, const _Float16* __restrict__ Kh,
             const _Float16* __restrict__ Vt, const unsigned char* __restrict__ Mg,
             float* __restrict__ Og)
{
    __shared__ _Float16 Kl[2][KT * Dn];     // 2 x 8 KB, XOR-swizzled chunks
    __shared__ _Float16 Vl[2][Dn * KT];     // 2 x 8 KB, XOR-swizzled chunks
    __shared__ _Float16 Pl[4][WQ * PSTR];   // per-wave P / mask staging, 18 KB

    const int tid  = threadIdx.x;
    const int wid  = tid >> 6;
    const int lane = tid & 63;
    const int l15  = lane & 15;
    const int quad = lane >> 4;

    const int bid = blockIdx.x;
    const int bh  = bid >> 4;
    const int qw0 = (bid & 15) * QTB + wid * WQ;

    // ---- Q fragments (pre-scaled f16): B-frag q=l15, k-dim = quad*8+j ----
    half8v qf[2][2];
#pragma unroll
    for (int qq = 0; qq < 2; ++qq) {
        const _Float16* src = Qh + ((size_t)(qw0 + qq * 16 + l15) * BHn + bh) * Dn + quad * 8;
#pragma unroll
        for (int c = 0; c < 2; ++c)
            qf[qq][c] = *(const half8v*)(src + 32 * c);
    }

    // ---- per-lane DMA global offsets (halves) ----
    const int rr = lane >> 3, ss = lane & 7, jj = ss ^ rr;   // row-in-8, slot, swizzled chunk
    const size_t koffG = ((size_t)(wid * 16 + rr) * BHn + bh) * Dn + jj * 8;
    const size_t voffG = ((size_t)bh * Dn + wid * 16 + rr) * SQn + jj * 8;

    // ---- swizzled LDS frag offsets (halves), loop-invariant ----
    int foff[4][2];
#pragma unroll
    for (int t4 = 0; t4 < 4; ++t4)
#pragma unroll
        for (int c = 0; c < 2; ++c) {
            const int r = t4 * 16 + l15;
            foff[t4][c] = r * 64 + ((c * 4 + quad) ^ (r & 7)) * 8;
        }

    const unsigned char* mp0 = Mg + (size_t)bh * SQn * SQn
                             + (size_t)(qw0 + (lane >> 1)) * SQn + (lane & 1) * 32;

    float mrun[2] = { -1e30f, -1e30f };
    float lrun[2] = { 0.f, 0.f };
    float4v otf[4][2];
#pragma unroll
    for (int td = 0; td < 4; ++td)
#pragma unroll
        for (int qq = 0; qq < 2; ++qq)
            otf[td][qq] = float4v{0.f, 0.f, 0.f, 0.f};

    uint4v mreg[2];
    auto dmaKV = [&](int kt, int buf) {
        const _Float16* gk = Kh + koffG + (size_t)kt * (KT * BHn * Dn);
        const _Float16* gv = Vt + voffG + (size_t)kt * KT;
        _Float16* lk = &Kl[buf][wid * 16 * 64];
        _Float16* lv = &Vl[buf][wid * 16 * 64];
        dma16(gk,                 lk);
        dma16(gk + 8 * BHn * Dn,  lk + 8 * 64);
        dma16(gv,                 lv);
        dma16(gv + 8 * SQn,       lv + 8 * 64);
    };
    auto loadmask = [&](int kt) {
        const unsigned char* mp = mp0 + kt * KT;
        mreg[0] = __builtin_nontemporal_load((const uint4v*)mp);
        mreg[1] = __builtin_nontemporal_load((const uint4v*)(mp + 16));
    };

    dmaKV(0, 0);
    loadmask(0);

    for (int kt = 0; kt < NT; ++kt) {
        const int buf = kt & 1;
        __syncthreads();   // drains DMA(kt); all waves done reading old tile in buf^1

        if (kt + 1 < NT) dmaKV(kt + 1, buf ^ 1);

        // ---- mask fast-path check (wave-uniform) ----
        unsigned int orv = mreg[0][0] | mreg[0][1] | mreg[0][2] | mreg[0][3]
                         | mreg[1][0] | mreg[1][1] | mreg[1][2] | mreg[1][3];
        const bool mflag = (__ballot(orv != 0u) != 0ull);
        if (mflag) {   // stage mask bytes in (not-yet-used) per-wave P region
            char* mr = (char*)&Pl[wid][0];
            *(uint4v*)(mr + (lane >> 1) * 64 + (lane & 1) * 32)      = mreg[0];
            *(uint4v*)(mr + (lane >> 1) * 64 + (lane & 1) * 32 + 16) = mreg[1];
        }

        // ---- S^T = K * Q^T : row=k_local=16tk+4quad+r, col=q=l15 ----
        const _Float16* Kb = Kl[buf];
        float4v st[4][2];
#pragma unroll
        for (int tk = 0; tk < 4; ++tk) {
            st[tk][0] = float4v{0.f, 0.f, 0.f, 0.f};
            st[tk][1] = float4v{0.f, 0.f, 0.f, 0.f};
#pragma unroll
            for (int c = 0; c < 2; ++c) {
                half8v ka = *(const half8v*)(Kb + foff[tk][c]);
                st[tk][0] = __builtin_amdgcn_mfma_f32_16x16x32_f16(ka, qf[0][c], st[tk][0], 0, 0, 0);
                st[tk][1] = __builtin_amdgcn_mfma_f32_16x16x32_f16(ka, qf[1][c], st[tk][1], 0, 0, 0);
            }
        }

        if (mflag) {
            const unsigned char* mr = (const unsigned char*)&Pl[wid][0];
#pragma unroll
            for (int qq = 0; qq < 2; ++qq)
#pragma unroll
                for (int tk = 0; tk < 4; ++tk)
#pragma unroll
                    for (int r = 0; r < 4; ++r)
                        if (mr[(qq * 16 + l15) * 64 + tk * 16 + quad * 4 + r])
                            st[tk][qq][r] = MASKV;
        }

        if (kt + 1 < NT) loadmask(kt + 1);

        // ---- online softmax in exp2 domain (q lane-resident) ----
#pragma unroll
        for (int qq = 0; qq < 2; ++qq) {
            float mx = -1e30f;
#pragma unroll
            for (int tk = 0; tk < 4; ++tk)
#pragma unroll
                for (int r = 0; r < 4; ++r) mx = fmaxf(mx, st[tk][qq][r]);
            mx = fmaxf(mx, __shfl_xor(mx, 16));
            mx = fmaxf(mx, __shfl_xor(mx, 32));
            const float mnew  = fmaxf(mrun[qq], mx);
            const float alpha = exp2f(mrun[qq] - mnew);
            mrun[qq] = mnew;

            float ls = 0.f;
#pragma unroll
            for (int tk = 0; tk < 4; ++tk) {
                float p0 = exp2f(st[tk][qq][0] - mnew);
                float p1 = exp2f(st[tk][qq][1] - mnew);
                float p2 = exp2f(st[tk][qq][2] - mnew);
                float p3 = exp2f(st[tk][qq][3] - mnew);
                ls += (p0 + p1) + (p2 + p3);
                half4v ph;
                ((half2v*)&ph)[0] = pkrtz(p0, p1);
                ((half2v*)&ph)[1] = pkrtz(p2, p3);
                *(half4v*)&Pl[wid][(qq * 16 + l15) * PSTR + tk * 16 + quad * 4] = ph;
            }
            ls += __shfl_xor(ls, 16);
            ls += __shfl_xor(ls, 32);
            lrun[qq] = lrun[qq] * alpha + ls;

#pragma unroll
            for (int td = 0; td < 4; ++td)
#pragma unroll
                for (int r = 0; r < 4; ++r) otf[td][qq][r] *= alpha;
        }

        // ---- O^T += V^T * P^T ----
        const _Float16* Vb = Vl[buf];
#pragma unroll
        for (int c2 = 0; c2 < 2; ++c2) {
            half8v pb0 = *(const half8v*)&Pl[wid][(l15) * PSTR + c2 * 32 + quad * 8];
            half8v pb1 = *(const half8v*)&Pl[wid][(16 + l15) * PSTR + c2 * 32 + quad * 8];
#pragma unroll
            for (int td = 0; td < 4; ++td) {
                half8v va = *(const half8v*)(Vb + foff[td][c2]);
                otf[td][0] = __builtin_amdgcn_mfma_f32_16x16x32_f16(va, pb0, otf[td][0], 0, 0, 0);
                otf[td][1] = __builtin_amdgcn_mfma_f32_16x16x32_f16(va, pb1, otf[td][1], 0, 0, 0);
            }
        }
    }

    // ---- epilogue: normalize by l, store ctx[q][b][h*64+d] ----
    const int b = bh >> 4, h = bh & 15;
#pragma unroll
    for (int qq = 0; qq < 2; ++qq) {
        const float inv  = 1.0f / lrun[qq];
        const int   qrow = qw0 + qq * 16 + l15;
        float* dst = Og + ((size_t)qrow * 2 + b) * 1024 + h * 64 + quad * 4;
#pragma unroll
        for (int td = 0; td < 4; ++td) {
            float4v o;
#pragma unroll
            for (int r = 0; r < 4; ++r) o[r] = otf[td][qq][r] * inv;
            *(float4v*)(dst + td * 16) = o;
        }
    }
}

extern "C" void kernel_launch(void* const* d_in, const int* in_sizes, int n_in,
                              void* d_out, int out_size, void* d_ws, size_t ws_size,
                              hipStream_t stream) {
    const float* Q = (const float*)d_in[0];
    const float* K = (const float*)d_in[1];
    const float* V = (const float*)d_in[2];
    const unsigned char* M = (const unsigned char*)d_in[3];
    float* O = (float*)d_out;

    constexpr size_t TN = (size_t)SQn * BHn * Dn;   // 4,194,304 elements
    _Float16* Qh = (_Float16*)d_ws;
    _Float16* Kh = Qh + TN;
    _Float16* Vt = Kh + TN;                          // 25.2 MB total in d_ws

    conv_qk<<<dim3(2 * TN / 8 / 256), dim3(256), 0, stream>>>(Q, K, Qh, Kh);
    trans_v<<<dim3(BHn * (SQn / 64)), dim3(256), 0, stream>>>(V, Vt);
    fa_main<<<dim3(16 * BHn), dim3(256), 0, stream>>>(Qh, Kh, Vt, M, O);
}